// Round 1
// baseline (48.084 us; speedup 1.0000x reference)
//
#include <hip/hip_runtime.h>

// MLS rigid deformation dense remap grid.
// Per pixel v=(x,y):
//   w_n = 1/(|p_n - v|^2 + 1e-9)
//   pstar = sum(w p)/sum(w); qstar = sum(w q)/sum(w)
//   a_n = ph·vp, b_n = phx*vpy - phy*vpx   (c = -b, d = a by algebra)
//   frv = (sum w(qhx a - qhy b), sum w(qhx b + qhy a))
//   out[y][x] = |vp| * frv/|frv| + qstar
#define IMG_H 768
#define IMG_W 768
#define NPTS 64

__global__ __launch_bounds__(256) void mls_deform_kernel(
    const float* __restrict__ pi,
    const float* __restrict__ qi,
    float* __restrict__ out)
{
    __shared__ float4 spq[NPTS];  // {px, py, qx, qy} per control point

    const int tid = threadIdx.x;
    if (tid < NPTS) {
        const float2 p = ((const float2*)pi)[tid];
        const float2 q = ((const float2*)qi)[tid];
        spq[tid] = make_float4(p.x, p.y, q.x, q.y);
    }
    __syncthreads();

    const int idx = blockIdx.x * 256 + tid;
    if (idx >= IMG_H * IMG_W) return;

    const int x = idx % IMG_W;   // column
    const int y = idx / IMG_W;   // row
    const float vx = (float)x;
    const float vy = (float)y;

    // Pass 1: weights + weighted centroids
    float sw = 0.f, spx = 0.f, spy = 0.f, sqx = 0.f, sqy = 0.f;
    #pragma unroll
    for (int n = 0; n < NPTS; ++n) {
        const float4 pq = spq[n];
        const float dx = pq.x - vx;
        const float dy = pq.y - vy;
        const float d2 = fmaf(dy, dy, fmaf(dx, dx, 1e-9f));
        const float w  = __builtin_amdgcn_rcpf(d2);
        sw  += w;
        spx = fmaf(w, pq.x, spx);
        spy = fmaf(w, pq.y, spy);
        sqx = fmaf(w, pq.z, sqx);
        sqy = fmaf(w, pq.w, sqy);
    }
    const float rsw = __builtin_amdgcn_rcpf(sw);
    const float psx = spx * rsw, psy = spy * rsw;   // pstar
    const float qsx = sqx * rsw, qsy = sqy * rsw;   // qstar

    const float vpx = vx - psx;
    const float vpy = vy - psy;

    // Pass 2: similarity contraction
    float fx = 0.f, fy = 0.f;
    #pragma unroll
    for (int n = 0; n < NPTS; ++n) {
        const float4 pq = spq[n];
        const float dx = pq.x - vx;
        const float dy = pq.y - vy;
        const float d2 = fmaf(dy, dy, fmaf(dx, dx, 1e-9f));
        const float w  = __builtin_amdgcn_rcpf(d2);
        const float phx = pq.x - psx;
        const float phy = pq.y - psy;
        const float qhx = pq.z - qsx;
        const float qhy = pq.w - qsy;
        const float a = fmaf(phx, vpx, phy * vpy);
        const float b = fmaf(phx, vpy, -phy * vpx);
        const float tx = fmaf(-qhy, b, qhx * a);
        const float ty = fmaf(qhy, a, qhx * b);
        fx = fmaf(w, tx, fx);
        fy = fmaf(w, ty, fy);
    }

    const float vpn = sqrtf(fmaf(vpx, vpx, vpy * vpy));
    const float fn  = sqrtf(fmaf(fx, fx, fy * fy)) + 1e-10f;
    const float s   = vpn * __builtin_amdgcn_rcpf(fn);
    const float ox  = fmaf(s, fx, qsx);
    const float oy  = fmaf(s, fy, qsy);

    ((float2*)out)[idx] = make_float2(ox, oy);
}

extern "C" void kernel_launch(void* const* d_in, const int* in_sizes, int n_in,
                              void* d_out, int out_size, void* d_ws, size_t ws_size,
                              hipStream_t stream) {
    // d_in[0] = img (unused for the remap grid), d_in[1] = pi (64,2) f32, d_in[2] = qi (64,2) f32
    const float* pi = (const float*)d_in[1];
    const float* qi = (const float*)d_in[2];
    float* out = (float*)d_out;

    const int npix = IMG_H * IMG_W;
    const int blocks = (npix + 255) / 256;
    mls_deform_kernel<<<blocks, 256, 0, stream>>>(pi, qi, out);
}

// Round 2
// 28.774 us; speedup vs baseline: 1.6711x; 1.6711x over previous
//
#include <hip/hip_runtime.h>

// MLS rigid deformation, fused single-pass complex form.
//
// Per pixel v: w_n = 1/(|p_n - v|^2 + 1e-9)
//   S = sum_n w_n q_n conj(p_n)  -  (sum w q) conj(sum w p) / sum w
//   pstar = (sum w p)/sw, qstar = (sum w q)/sw, vp = v - pstar
//   frv = vp * S  (complex mult);  out = |vp| * frv/|frv| + qstar
//
// Per-point constants {px,py,qx,qy,cre,cim} precomputed into d_ws and read at
// uniform compile-time addresses -> s_load into SGPRs; hot loop is pure VALU.

#define IMG_H 768
#define IMG_W 768
#define NPTS 64

__global__ void mls_precompute(const float* __restrict__ pi,
                               const float* __restrict__ qi,
                               float* __restrict__ cst)
{
    const int n = threadIdx.x;
    if (n >= NPTS) return;
    const float px = pi[2 * n + 0];
    const float py = pi[2 * n + 1];
    const float qx = qi[2 * n + 0];
    const float qy = qi[2 * n + 1];
    cst[8 * n + 0] = px;
    cst[8 * n + 1] = py;
    cst[8 * n + 2] = qx;
    cst[8 * n + 3] = qy;
    cst[8 * n + 4] = fmaf(qx, px, qy * py);   // Re(q conj p)
    cst[8 * n + 5] = fmaf(qy, px, -qx * py);  // Im(q conj p)
    cst[8 * n + 6] = 0.f;
    cst[8 * n + 7] = 0.f;
}

__device__ __forceinline__ float2 mls_finish(
    float vxk, float vy,
    float sw, float spx, float spy, float sqx, float sqy,
    float sre, float sim)
{
    const float rsw = __builtin_amdgcn_rcpf(sw);
    const float psx = spx * rsw, psy = spy * rsw;   // pstar
    const float qsx = sqx * rsw, qsy = sqy * rsw;   // qstar
    // S = (sre,sim) - swq * conj(swp) / sw
    const float cre = fmaf(sqx, spx, sqy * spy) * rsw;
    const float cim = fmaf(sqy, spx, -sqx * spy) * rsw;
    const float Sre = sre - cre;
    const float Sim = sim - cim;
    const float vpx = vxk - psx;
    const float vpy = vy - psy;
    const float frx = fmaf(vpx, Sre, -vpy * Sim);
    const float fry = fmaf(vpx, Sim, vpy * Sre);
    const float vpn = sqrtf(fmaf(vpx, vpx, vpy * vpy));
    const float frn = sqrtf(fmaf(frx, frx, fry * fry)) + 1e-10f;
    const float s = vpn * __builtin_amdgcn_rcpf(frn);
    return make_float2(fmaf(s, frx, qsx), fmaf(s, fry, qsy));
}

__global__ __launch_bounds__(256) void mls_main(
    const float* __restrict__ cst,
    float* __restrict__ out)
{
    const int idx = blockIdx.x * 256 + threadIdx.x;   // one thread = 2 pixels
    const int xh = idx % (IMG_W / 2);
    const int y  = idx / (IMG_W / 2);
    const float vx = (float)(2 * xh);
    const float vy = (float)y;

    float sw0 = 0.f, spx0 = 0.f, spy0 = 0.f, sqx0 = 0.f, sqy0 = 0.f, sre0 = 0.f, sim0 = 0.f;
    float sw1 = 0.f, spx1 = 0.f, spy1 = 0.f, sqx1 = 0.f, sqy1 = 0.f, sre1 = 0.f, sim1 = 0.f;

    #pragma unroll
    for (int n = 0; n < NPTS; ++n) {
        const float px  = cst[8 * n + 0];
        const float py  = cst[8 * n + 1];
        const float qx  = cst[8 * n + 2];
        const float qy  = cst[8 * n + 3];
        const float cre = cst[8 * n + 4];
        const float cim = cst[8 * n + 5];

        const float dx = px - vx;
        const float dy = py - vy;
        const float t  = fmaf(dy, dy, 1e-9f);
        const float d0 = fmaf(dx, dx, t);
        const float d1 = fmaf(-2.f, dx, d0) + 1.0f;   // d2 at x+1
        const float w0 = __builtin_amdgcn_rcpf(d0);
        const float w1 = __builtin_amdgcn_rcpf(d1);

        sw0  += w0;                     sw1  += w1;
        spx0 = fmaf(w0, px,  spx0);     spx1 = fmaf(w1, px,  spx1);
        spy0 = fmaf(w0, py,  spy0);     spy1 = fmaf(w1, py,  spy1);
        sqx0 = fmaf(w0, qx,  sqx0);     sqx1 = fmaf(w1, qx,  sqx1);
        sqy0 = fmaf(w0, qy,  sqy0);     sqy1 = fmaf(w1, qy,  sqy1);
        sre0 = fmaf(w0, cre, sre0);     sre1 = fmaf(w1, cre, sre1);
        sim0 = fmaf(w0, cim, sim0);     sim1 = fmaf(w1, cim, sim1);
    }

    const float2 r0 = mls_finish(vx,       vy, sw0, spx0, spy0, sqx0, sqy0, sre0, sim0);
    const float2 r1 = mls_finish(vx + 1.f, vy, sw1, spx1, spy1, sqx1, sqy1, sre1, sim1);

    ((float4*)out)[idx] = make_float4(r0.x, r0.y, r1.x, r1.y);
}

extern "C" void kernel_launch(void* const* d_in, const int* in_sizes, int n_in,
                              void* d_out, int out_size, void* d_ws, size_t ws_size,
                              hipStream_t stream) {
    // d_in[0] = img (unused), d_in[1] = pi (64,2) f32, d_in[2] = qi (64,2) f32
    const float* pi = (const float*)d_in[1];
    const float* qi = (const float*)d_in[2];
    float* cst = (float*)d_ws;     // 64 * 8 floats = 2 KB
    float* out = (float*)d_out;

    mls_precompute<<<1, 64, 0, stream>>>(pi, qi, cst);

    const int nthreads = IMG_H * (IMG_W / 2);   // 294912, two pixels per thread
    mls_main<<<nthreads / 256, 256, 0, stream>>>(cst, out);
}

// Round 3
// 19.334 us; speedup vs baseline: 2.4870x; 1.4883x over previous
//
#include <hip/hip_runtime.h>

// MLS rigid deformation, fused single-pass complex form, zero-memory inner loop.
//
// Per pixel v: w_n = 1/(|p_n - v|^2 + 1e-9)
//   S = sum_n w_n q_n conj(p_n)  -  (sum w q) conj(sum w p) / sum w
//   pstar = (sum w p)/sw, qstar = (sum w q)/sw, vp = v - pstar
//   frv = vp * S  (complex mult);  out = |vp| * frv/|frv| + qstar
//
// NPTS == 64 == wave width: lane n holds point n's constants in VGPRs;
// the fully-unrolled loop broadcasts them with v_readlane (imm lane) ->
// SGPR operands. No LDS, no loads, no second kernel. 3 pixels/thread,
// one block per image row -> 768 blocks = exactly 3 blocks/CU.

#define IMG_H 768
#define IMG_W 768
#define NPTS 64

__device__ __forceinline__ float rdlane(float v, int lane) {
    return __int_as_float(__builtin_amdgcn_readlane(__float_as_int(v), lane));
}

__device__ __forceinline__ float2 mls_finish(
    float vxk, float vy,
    float sw, float spx, float spy, float sqx, float sqy,
    float sre, float sim)
{
    const float rsw = __builtin_amdgcn_rcpf(sw);
    const float psx = spx * rsw, psy = spy * rsw;   // pstar
    const float qsx = sqx * rsw, qsy = sqy * rsw;   // qstar
    // S = (sre,sim) - swq * conj(swp) / sw
    const float cre = fmaf(sqx, spx, sqy * spy) * rsw;
    const float cim = fmaf(sqy, spx, -sqx * spy) * rsw;
    const float Sre = sre - cre;
    const float Sim = sim - cim;
    const float vpx = vxk - psx;
    const float vpy = vy - psy;
    const float frx = fmaf(vpx, Sre, -vpy * Sim);
    const float fry = fmaf(vpx, Sim, vpy * Sre);
    const float vpn = sqrtf(fmaf(vpx, vpx, vpy * vpy));
    const float frn = sqrtf(fmaf(frx, frx, fry * fry)) + 1e-10f;
    const float s = vpn * __builtin_amdgcn_rcpf(frn);
    return make_float2(fmaf(s, frx, qsx), fmaf(s, fry, qsy));
}

__global__ __launch_bounds__(256) void mls_main(
    const float* __restrict__ pi,
    const float* __restrict__ qi,
    float* __restrict__ out)
{
    const int tid  = threadIdx.x;
    const int lane = tid & 63;

    // Lane n holds point n's constants (all waves load the same 64 points; L1 hit).
    const float2 p = ((const float2*)pi)[lane];
    const float2 q = ((const float2*)qi)[lane];
    const float lpx = p.x, lpy = p.y, lqx = q.x, lqy = q.y;
    const float lcre = fmaf(q.x, p.x,  q.y * p.y);   // Re(q conj p)
    const float lcim = fmaf(q.y, p.x, -q.x * p.y);   // Im(q conj p)

    const int y = blockIdx.x;                 // one block per row
    const float vy = (float)y;
    const float vx = (float)(3 * tid);        // 256 threads * 3 px = 768 = IMG_W

    float sw0 = 0.f, spx0 = 0.f, spy0 = 0.f, sqx0 = 0.f, sqy0 = 0.f, sre0 = 0.f, sim0 = 0.f;
    float sw1 = 0.f, spx1 = 0.f, spy1 = 0.f, sqx1 = 0.f, sqy1 = 0.f, sre1 = 0.f, sim1 = 0.f;
    float sw2 = 0.f, spx2 = 0.f, spy2 = 0.f, sqx2 = 0.f, sqy2 = 0.f, sre2 = 0.f, sim2 = 0.f;

    #pragma unroll
    for (int n = 0; n < NPTS; ++n) {
        const float px  = rdlane(lpx,  n);
        const float py  = rdlane(lpy,  n);
        const float qx  = rdlane(lqx,  n);
        const float qy  = rdlane(lqy,  n);
        const float cre = rdlane(lcre, n);
        const float cim = rdlane(lcim, n);

        const float dx = px - vx;
        const float dy = py - vy;
        const float t  = fmaf(dy, dy, 1e-9f);
        const float d0 = fmaf(dx, dx, t);
        const float d1 = fmaf(-2.f, dx, d0) + 1.0f;   // |p - (v+1,vy)|^2
        const float d2 = fmaf(-4.f, dx, d0) + 4.0f;   // |p - (v+2,vy)|^2
        const float w0 = __builtin_amdgcn_rcpf(d0);
        const float w1 = __builtin_amdgcn_rcpf(d1);
        const float w2 = __builtin_amdgcn_rcpf(d2);

        sw0  += w0;                   sw1  += w1;                   sw2  += w2;
        spx0 = fmaf(w0, px,  spx0);   spx1 = fmaf(w1, px,  spx1);   spx2 = fmaf(w2, px,  spx2);
        spy0 = fmaf(w0, py,  spy0);   spy1 = fmaf(w1, py,  spy1);   spy2 = fmaf(w2, py,  spy2);
        sqx0 = fmaf(w0, qx,  sqx0);   sqx1 = fmaf(w1, qx,  sqx1);   sqx2 = fmaf(w2, qx,  sqx2);
        sqy0 = fmaf(w0, qy,  sqy0);   sqy1 = fmaf(w1, qy,  sqy1);   sqy2 = fmaf(w2, qy,  sqy2);
        sre0 = fmaf(w0, cre, sre0);   sre1 = fmaf(w1, cre, sre1);   sre2 = fmaf(w2, cre, sre2);
        sim0 = fmaf(w0, cim, sim0);   sim1 = fmaf(w1, cim, sim1);   sim2 = fmaf(w2, cim, sim2);
    }

    const float2 r0 = mls_finish(vx,       vy, sw0, spx0, spy0, sqx0, sqy0, sre0, sim0);
    const float2 r1 = mls_finish(vx + 1.f, vy, sw1, spx1, spy1, sqx1, sqy1, sre1, sim1);
    const float2 r2 = mls_finish(vx + 2.f, vy, sw2, spx2, spy2, sqx2, sqy2, sre2, sim2);

    float2* orow = (float2*)out + (size_t)y * IMG_W + 3 * tid;
    orow[0] = r0;
    orow[1] = r1;
    orow[2] = r2;
}

extern "C" void kernel_launch(void* const* d_in, const int* in_sizes, int n_in,
                              void* d_out, int out_size, void* d_ws, size_t ws_size,
                              hipStream_t stream) {
    // d_in[0] = img (unused), d_in[1] = pi (64,2) f32, d_in[2] = qi (64,2) f32
    const float* pi = (const float*)d_in[1];
    const float* qi = (const float*)d_in[2];
    float* out = (float*)d_out;

    mls_main<<<IMG_H, 256, 0, stream>>>(pi, qi, out);
}